// Round 8
// baseline (71.473 us; speedup 1.0000x reference)
//
#include <hip/hip_runtime.h>
#include <math.h>

#define HW 4096
#define NCH 4
#define TPB 256
#define ROWS_PER_BLOCK 16
#define BLOCKS_PER_CH (HW / ROWS_PER_BLOCK)   // 256
#define NBLOCKS (NCH * BLOCKS_PER_CH)         // 1024
#define KNN 5

#define NBINS 512
#define BLO   (-5.0f)
#define BINV  51.2f            // NBINS / 10
#define BDELTA 0.01953125f     // 10 / 512
#define SLOP  1e-5f            // >> fp rounding of edge math, << BDELTA
#define INFT  3.4e38f

// ws layout (float index): bxx[4ch][4096] @0, bxy @16384, by @32768,
// prefX int @49152 (4*513), prefY int @49152+4*513, partials @57344.
#define WS_BXY   16384
#define WS_BY    32768
#define WS_PREF  49152
#define WS_PART  57344

__device__ __forceinline__ int binOf(float v) {
    int b = (int)floorf((v - BLO) * BINV);
    return min(max(b, 0), NBINS - 1);
}

// digamma for positive args (integers here). Shift to >= 6 + asymptotic.
__device__ __forceinline__ float digammaf_dev(float x) {
    float r = 0.f;
    while (x < 6.f) { r -= 1.f / x; x += 1.f; }
    float f = 1.f / x, f2 = f * f;
    return logf(x) - 0.5f * f
         - f2 * (1.f / 12.f - f2 * (1.f / 120.f - f2 * (1.f / 252.f))) + r;
}

// Insert d into ascending sorted 6-list (drop max): 6 independent med3.
__device__ __forceinline__ void insert6(float (&s)[6], float d) {
    float n0 = fminf(s[0], d);
    float n1 = __builtin_amdgcn_fmed3f(s[0], s[1], d);
    float n2 = __builtin_amdgcn_fmed3f(s[1], s[2], d);
    float n3 = __builtin_amdgcn_fmed3f(s[2], s[3], d);
    float n4 = __builtin_amdgcn_fmed3f(s[3], s[4], d);
    float n5 = __builtin_amdgcn_fmed3f(s[4], s[5], d);
    s[0] = n0; s[1] = n1; s[2] = n2; s[3] = n3; s[4] = n4; s[5] = n5;
}

// ---------------- Kernel 0: per-channel bucketize (counting sort) ----------
__global__ __launch_bounds__(TPB) void knnmi_bucketize(const float* __restrict__ x,
                                                       const float* __restrict__ y,
                                                       float* __restrict__ ws) {
    __shared__ int h[NBINS], tmp[NBINS], cur[NBINS];
    const int c = blockIdx.x;
    const int t = threadIdx.x;
    const float* xc = x + c * HW;
    const float* yc = y + c * HW;
    float* bxx = ws + c * HW;
    float* bxy = ws + WS_BXY + c * HW;
    float* by  = ws + WS_BY  + c * HW;
    int* prefx = (int*)ws + WS_PREF + c * (NBINS + 1);
    int* prefy = (int*)ws + WS_PREF + NCH * (NBINS + 1) + c * (NBINS + 1);

    // ---- X side: histogram -> scan -> scatter pairs ----
    for (int i = t; i < NBINS; i += TPB) h[i] = 0;
    __syncthreads();
    for (int i = t; i < HW; i += TPB) atomicAdd(&h[binOf(xc[i])], 1);
    __syncthreads();
    for (int off = 1; off < NBINS; off <<= 1) {
        for (int i = t; i < NBINS; i += TPB)
            tmp[i] = h[i] + ((i >= off) ? h[i - off] : 0);
        __syncthreads();
        for (int i = t; i < NBINS; i += TPB) h[i] = tmp[i];
        __syncthreads();
    }
    for (int i = t; i < NBINS; i += TPB) {
        int e = (i == 0) ? 0 : h[i - 1];
        prefx[i] = e;
        cur[i] = e;
    }
    if (t == 0) prefx[NBINS] = h[NBINS - 1];
    __syncthreads();
    for (int i = t; i < HW; i += TPB) {
        float xv = xc[i], yv = yc[i];
        int pos = atomicAdd(&cur[binOf(xv)], 1);
        bxx[pos] = xv;
        bxy[pos] = yv;
    }
    __syncthreads();

    // ---- Y side: histogram -> scan -> scatter values ----
    for (int i = t; i < NBINS; i += TPB) h[i] = 0;
    __syncthreads();
    for (int i = t; i < HW; i += TPB) atomicAdd(&h[binOf(yc[i])], 1);
    __syncthreads();
    for (int off = 1; off < NBINS; off <<= 1) {
        for (int i = t; i < NBINS; i += TPB)
            tmp[i] = h[i] + ((i >= off) ? h[i - off] : 0);
        __syncthreads();
        for (int i = t; i < NBINS; i += TPB) h[i] = tmp[i];
        __syncthreads();
    }
    for (int i = t; i < NBINS; i += TPB) {
        int e = (i == 0) ? 0 : h[i - 1];
        prefy[i] = e;
        cur[i] = e;
    }
    if (t == 0) prefy[NBINS] = h[NBINS - 1];
    __syncthreads();
    for (int i = t; i < HW; i += TPB) {
        float yv = yc[i];
        int pos = atomicAdd(&cur[binOf(yv)], 1);
        by[pos] = yv;
    }
}

// ---------------- Kernel 1: windowed kNN + bucket counts --------------------
__global__ __launch_bounds__(TPB, 4) void knnmi_rows(float* __restrict__ ws) {
    __shared__ float2 sxy[HW];          // 32 KB bin-grouped {x,y} pairs
    __shared__ int pfx[NBINS + 1];
    __shared__ float red[ROWS_PER_BLOCK];

    const int c  = blockIdx.x >> 8;
    const int rb = blockIdx.x & 255;
    const float* bxx = ws + c * HW;
    const float* bxy = ws + WS_BXY + c * HW;
    const float* by  = ws + WS_BY  + c * HW;
    const int* prefx = (const int*)ws + WS_PREF + c * (NBINS + 1);
    const int* prefy = (const int*)ws + WS_PREF + NCH * (NBINS + 1) + c * (NBINS + 1);
    float* partials  = ws + WS_PART;

    for (int i = threadIdx.x; i < HW / 4; i += TPB) {
        float4 xv = ((const float4*)bxx)[i];
        float4 yv = ((const float4*)bxy)[i];
        ((float4*)sxy)[2 * i]     = make_float4(xv.x, yv.x, xv.y, yv.y);
        ((float4*)sxy)[2 * i + 1] = make_float4(xv.z, yv.z, xv.w, yv.w);
    }
    for (int i = threadIdx.x; i <= NBINS; i += TPB) pfx[i] = prefx[i];
    __syncthreads();

    const int wv   = threadIdx.x >> 6;
    const int lane = threadIdx.x & 63;
    const int l    = lane & 15;          // lane within 16-lane group
    const int g    = lane >> 4;          // group (row) within wave
    const int p    = rb * ROWS_PER_BLOCK + wv * 4 + g;   // row = grouped index

    const float xi = sxy[p].x;
    const float yi = sxy[p].y;
    const int myB  = binOf(xi);

    float s[6];
#pragma unroll
    for (int q = 0; q < 6; ++q) s[q] = INFT;

    // Own bin (contains self -> d=0 inserted exactly once).
    const int oLo = pfx[myB], oHi = pfx[myB + 1];
    for (int tt = oLo + l; tt < oHi; tt += 16) {
        float2 pp = sxy[tt];
        insert6(s, fmaxf(fabsf(xi - pp.x), fabsf(yi - pp.y)));
    }

    // Expand 16 candidates per side per iter; exact bin-edge early exit.
    int idxL = oLo, idxR = oHi;
    for (int w = 0; w < 300; ++w) {
        int newL = max(idxL - 16, 0);
        int newR = min(idxR + 16, HW);
        int tL = newL + l;
        int tR = idxR + l;
        float2 pL = sxy[tL];                      // tL in [0,HW) always
        float2 pR = sxy[min(tR, HW - 1)];
        float dL = (tL < idxL) ? fmaxf(fabsf(xi - pL.x), fabsf(yi - pL.y)) : INFT;
        float dR = (tR < newR) ? fmaxf(fabsf(xi - pR.x), fabsf(yi - pR.y)) : INFT;
        insert6(s, dL);
        insert6(s, dR);
        idxL = newL; idxR = newR;

        // Conservative bounds on any unscanned point's fl|dx|.
        float edgeL = (idxL == 0) ? INFT
            : (xi - (BLO + (float)(binOf(sxy[max(idxL - 1, 0)].x) + 1) * BDELTA + SLOP));
        float edgeR = (idxR >= HW) ? INFT
            : ((BLO + (float)binOf(sxy[min(idxR, HW - 1)].x) * BDELTA - SLOP) - xi);

        // Converged when edge >= min-lane s[5] (>= merged s[5]) on both sides.
        unsigned long long mL = __ballot(s[5] <= edgeL);
        unsigned long long mR = __ballot(s[5] <= edgeR);
        int gb = lane & 48;
        bool conv = (((mL >> gb) & 0xFFFFull) != 0ull) &&
                    (((mR >> gb) & 0xFFFFull) != 0ull);
        if (__all(conv)) break;
    }

    // Merge the 16 per-lane sorted 6-lists (4 butterfly stages).
#pragma unroll
    for (int m = 1; m < 16; m <<= 1) {
        float o[6];
#pragma unroll
        for (int q = 0; q < 6; ++q) o[q] = __shfl_xor(s[q], m);
#pragma unroll
        for (int q = 0; q < 6; ++q) insert6(s, o[q]);
    }
    const float eps = s[5];   // exact (k+1)-th smallest joint distance

    // ---- nx: full bins via prefix + exact strict-< scan of boundary bins ----
    int nx = 0;
    {
        int loB = binOf(xi - eps), hiB = binOf(xi + eps);
        int fLo = loB + 2, fHi = hiB - 2;
        if (fLo <= fHi) {
            if (l == 0) nx += pfx[fHi + 1] - pfx[fLo];
            int a0 = pfx[max(loB - 1, 0)], a1 = pfx[min(loB + 1, NBINS - 1) + 1];
            int b0 = pfx[max(hiB - 1, 0)], b1 = pfx[min(hiB + 1, NBINS - 1) + 1];
            for (int tt = a0 + l; tt < a1; tt += 16) nx += (fabsf(sxy[tt].x - xi) < eps);
            for (int tt = b0 + l; tt < b1; tt += 16) nx += (fabsf(sxy[tt].x - xi) < eps);
        } else {
            int a0 = pfx[max(loB - 1, 0)], a1 = pfx[min(hiB + 1, NBINS - 1) + 1];
            for (int tt = a0 + l; tt < a1; tt += 16) nx += (fabsf(sxy[tt].x - xi) < eps);
        }
    }

    // ---- ny: same scheme on the y-bucketed array (global, L2-hot) ----
    int ny = 0;
    {
        int loB = binOf(yi - eps), hiB = binOf(yi + eps);
        int fLo = loB + 2, fHi = hiB - 2;
        if (fLo <= fHi) {
            if (l == 0) ny += prefy[fHi + 1] - prefy[fLo];
            int a0 = prefy[max(loB - 1, 0)], a1 = prefy[min(loB + 1, NBINS - 1) + 1];
            int b0 = prefy[max(hiB - 1, 0)], b1 = prefy[min(hiB + 1, NBINS - 1) + 1];
            for (int tt = a0 + l; tt < a1; tt += 16) ny += (fabsf(by[tt] - yi) < eps);
            for (int tt = b0 + l; tt < b1; tt += 16) ny += (fabsf(by[tt] - yi) < eps);
        } else {
            int a0 = prefy[max(loB - 1, 0)], a1 = prefy[min(hiB + 1, NBINS - 1) + 1];
            for (int tt = a0 + l; tt < a1; tt += 16) ny += (fabsf(by[tt] - yi) < eps);
        }
    }

    // Group-reduce counts (each <= 4096: pack 16+16 bit).
    int pk = (nx << 16) | ny;
#pragma unroll
    for (int m = 1; m < 16; m <<= 1) pk += __shfl_xor(pk, m);

    if (l == 0)
        red[wv * 4 + g] = digammaf_dev((float)(pk >> 16))
                        + digammaf_dev((float)(pk & 0xffff));
    __syncthreads();

    if (threadIdx.x == 0) {
        float v = 0.f;
#pragma unroll
        for (int q = 0; q < ROWS_PER_BLOCK; ++q) v += red[q];
        partials[blockIdx.x] = v;
    }
}

// ---------------- Kernel 2: finalize ----------------------------------------
__global__ void knnmi_final(const float* __restrict__ ws, float* __restrict__ out) {
    const float* partials = ws + WS_PART;
    const int w    = threadIdx.x >> 6;    // wave = channel
    const int lane = threadIdx.x & 63;
    float sum = 0.f;
#pragma unroll
    for (int i = lane; i < BLOCKS_PER_CH; i += 64)
        sum += partials[w * BLOCKS_PER_CH + i];
#pragma unroll
    for (int m = 32; m; m >>= 1) sum += __shfl_xor(sum, m);
    if (lane == 0) {
        float mi = digammaf_dev((float)KNN) + digammaf_dev((float)HW)
                 - sum / (float)HW;
        out[w] = fmaxf(mi, 0.f);
    }
}

extern "C" void kernel_launch(void* const* d_in, const int* in_sizes, int n_in,
                              void* d_out, int out_size, void* d_ws, size_t ws_size,
                              hipStream_t stream) {
    const float* x = (const float*)d_in[0];
    const float* y = (const float*)d_in[1];
    float* out = (float*)d_out;
    float* ws  = (float*)d_ws;   // all read regions fully rewritten every call

    knnmi_bucketize<<<NCH, TPB, 0, stream>>>(x, y, ws);
    knnmi_rows<<<NBLOCKS, TPB, 0, stream>>>(ws);
    knnmi_final<<<1, NCH * 64, 0, stream>>>(ws, out);
}

// Round 9
// 63.476 us; speedup vs baseline: 1.1260x; 1.1260x over previous
//
#include <hip/hip_runtime.h>
#include <math.h>

#define HW 4096
#define NCH 4
#define TPB 256
#define RPB 32                                // rows per block (2 passes x 16)
#define BLOCKS_PER_CH 128
#define NBLOCKS (NCH * BLOCKS_PER_CH)         // 512
#define KNN 5

#define NBINS 512
#define BLO   (-6.0f)
#define BDELTA 0.0234375f      // 12/512, exact in fp32
#define BINV  (512.0f / 12.0f)
#define SLOP  1e-5f            // >> fp rounding of bin/edge math, << BDELTA
#define INFT  3.4e38f

// ws layout (float idx): bxx[4][4096]@0, bxy@16384, by@32768,
// prefX int@49152 (4*513), prefY after it, partials@57344 (512 floats).
#define WS_BXY   16384
#define WS_BY    32768
#define WS_PREF  49152
#define WS_PART  57344

__device__ __forceinline__ int binOf(float v) {
    int b = (int)floorf((v - BLO) * BINV);
    return min(max(b, 0), NBINS - 1);
}

// digamma for positive integer args. Shift to >= 6 + asymptotic. ~1e-7.
__device__ __forceinline__ float digammaf_dev(float x) {
    float r = 0.f;
    while (x < 6.f) { r -= 1.f / x; x += 1.f; }
    float f = 1.f / x, f2 = f * f;
    return logf(x) - 0.5f * f
         - f2 * (1.f / 12.f - f2 * (1.f / 120.f - f2 * (1.f / 252.f))) + r;
}

// Insert d into ascending sorted 6-list (drop max): 6 independent med3.
__device__ __forceinline__ void insert6(float (&s)[6], float d) {
    float n0 = fminf(s[0], d);
    float n1 = __builtin_amdgcn_fmed3f(s[0], s[1], d);
    float n2 = __builtin_amdgcn_fmed3f(s[1], s[2], d);
    float n3 = __builtin_amdgcn_fmed3f(s[2], s[3], d);
    float n4 = __builtin_amdgcn_fmed3f(s[3], s[4], d);
    float n5 = __builtin_amdgcn_fmed3f(s[4], s[5], d);
    s[0] = n0; s[1] = n1; s[2] = n2; s[3] = n3; s[4] = n4; s[5] = n5;
}

// --------- Kernel 0: bucketize; 8 blocks = (channel x side) ---------------
__global__ __launch_bounds__(1024) void knnmi_bucketize(const float* __restrict__ x,
                                                        const float* __restrict__ y,
                                                        float* __restrict__ ws) {
    __shared__ int h[NBINS], tmp[NBINS], cur[NBINS];
    const int c    = blockIdx.x >> 1;
    const int side = blockIdx.x & 1;              // 0 = X pairs, 1 = Y values
    const int t    = threadIdx.x;
    const float* src = (side == 0 ? x : y) + c * HW;

    for (int i = t; i < NBINS; i += 1024) h[i] = 0;
    __syncthreads();
    for (int i = t; i < HW; i += 1024) atomicAdd(&h[binOf(src[i])], 1);
    __syncthreads();
    for (int off = 1; off < NBINS; off <<= 1) {
        for (int i = t; i < NBINS; i += 1024)
            tmp[i] = h[i] + ((i >= off) ? h[i - off] : 0);
        __syncthreads();
        for (int i = t; i < NBINS; i += 1024) h[i] = tmp[i];
        __syncthreads();
    }
    int* pref = (int*)ws + WS_PREF + (side ? NCH * (NBINS + 1) : 0) + c * (NBINS + 1);
    for (int i = t; i < NBINS; i += 1024) {
        int e = i ? h[i - 1] : 0;
        pref[i] = e;
        cur[i] = e;
    }
    if (t == 0) pref[NBINS] = h[NBINS - 1];
    __syncthreads();
    if (side == 0) {
        const float* yc = y + c * HW;
        float* bxx = ws + c * HW;
        float* bxy = ws + WS_BXY + c * HW;
        for (int i = t; i < HW; i += 1024) {
            float xv = src[i];
            int pos = atomicAdd(&cur[binOf(xv)], 1);
            bxx[pos] = xv;
            bxy[pos] = yc[i];
        }
    } else {
        float* by = ws + WS_BY + c * HW;
        for (int i = t; i < HW; i += 1024) {
            float yv = src[i];
            int pos = atomicAdd(&cur[binOf(yv)], 1);
            by[pos] = yv;
        }
    }
}

// --------- Kernel 1: windowed kNN + bucket counts -------------------------
__global__ __launch_bounds__(TPB, 2) void knnmi_rows(float* __restrict__ ws) {
    __shared__ float2 sxy[HW];            // 32 KB x-bucketed {x,y}
    __shared__ float  ys[HW];             // 16 KB y-bucketed values
    __shared__ int pfx[NBINS + 1], pfy[NBINS + 1];
    __shared__ float red[16];

    const int c  = blockIdx.x >> 7;       // channel
    const int rb = blockIdx.x & 127;      // block within channel
    const float* bxx = ws + c * HW;
    const float* bxy = ws + WS_BXY + c * HW;
    const float* by  = ws + WS_BY  + c * HW;
    const int* prefx = (const int*)ws + WS_PREF + c * (NBINS + 1);
    const int* prefy = (const int*)ws + WS_PREF + NCH * (NBINS + 1) + c * (NBINS + 1);

    for (int i = threadIdx.x; i < HW / 4; i += TPB) {
        float4 xv = ((const float4*)bxx)[i];
        float4 yv = ((const float4*)bxy)[i];
        ((float4*)sxy)[2 * i]     = make_float4(xv.x, yv.x, xv.y, yv.y);
        ((float4*)sxy)[2 * i + 1] = make_float4(xv.z, yv.z, xv.w, yv.w);
        ((float4*)ys)[i] = ((const float4*)by)[i];
    }
    for (int i = threadIdx.x; i <= NBINS; i += TPB) {
        pfx[i] = prefx[i];
        pfy[i] = prefy[i];
    }
    __syncthreads();

    const int wv   = threadIdx.x >> 6;
    const int lane = threadIdx.x & 63;
    const int l    = lane & 15;           // lane within 16-lane group
    const int g    = lane >> 4;           // group within wave

    float acc = 0.f;

    for (int pass = 0; pass < 2; ++pass) {
        const int q = pass * 16 + wv * 4 + g;     // 0..31
        const int p = rb + 128 * q;               // stratified row index
        const float xi = sxy[p].x;
        const float yi = sxy[p].y;
        const int myB  = binOf(xi);

        float s[6];
#pragma unroll
        for (int k = 0; k < 6; ++k) s[k] = INFT;

        // Own bin (contains self -> d=0 inserted exactly once).
        const int oLo = pfx[myB], oHi = pfx[myB + 1];
        for (int tt = oLo + l; tt < oHi; tt += 16) {
            float2 pp = sxy[tt];
            insert6(s, fmaxf(fabsf(xi - pp.x), fabsf(yi - pp.y)));
        }

        int wL = oLo, wR = oHi;
        bool lD = (wL <= 0), rD = (wR >= HW);

        for (int guard = 0; guard < 140; ++guard) {
            if (__all(lD && rD)) break;
            if (!lD) {                            // group-uniform branch
                int t0 = wL - 32 + l, t1 = wL - 16 + l;
                float2 p0 = sxy[max(t0, 0)];
                float2 p1 = sxy[max(t1, 0)];
                if (t0 >= 0) insert6(s, fmaxf(fabsf(xi - p0.x), fabsf(yi - p0.y)));
                if (t1 >= 0) insert6(s, fmaxf(fabsf(xi - p1.x), fabsf(yi - p1.y)));
                wL = max(wL - 32, 0);
            }
            if (!rD) {
                int t0 = wR + l, t1 = wR + 16 + l;
                float2 p0 = sxy[min(t0, HW - 1)];
                float2 p1 = sxy[min(t1, HW - 1)];
                if (t0 < HW) insert6(s, fmaxf(fabsf(xi - p0.x), fabsf(yi - p0.y)));
                if (t1 < HW) insert6(s, fmaxf(fabsf(xi - p1.x), fabsf(yi - p1.y)));
                wR = min(wR + 32, HW);
            }
            // Conservative lower bounds on unscanned fl|dx| per side.
            float eL = INFT, eR = INFT;
            if (!lD && wL > 0) {
                int b = binOf(sxy[wL - 1].x);
                eL = xi - (BLO + (float)(b + 1) * BDELTA + SLOP);
            }
            if (!rD && wR < HW) {
                int b = binOf(sxy[wR].x);
                eR = (BLO + (float)b * BDELTA - SLOP) - xi;
            }
            // Exact exit: >=6 retained candidates <= edge  =>  merged s5 <= edge.
            int cl = 0, cr = 0;
#pragma unroll
            for (int k = 0; k < 6; ++k) { cl += (s[k] <= eL); cr += (s[k] <= eR); }
#pragma unroll
            for (int m = 1; m < 16; m <<= 1) {
                cl += __shfl_xor(cl, m);
                cr += __shfl_xor(cr, m);
            }
            lD = lD || (wL <= 0) || (cl >= 6);
            rD = rD || (wR >= HW) || (cr >= 6);
        }

        // Merge the 16 per-lane sorted 6-lists (4 butterfly stages).
#pragma unroll
        for (int m = 1; m < 16; m <<= 1) {
            float o[6];
#pragma unroll
            for (int k = 0; k < 6; ++k) o[k] = __shfl_xor(s[k], m);
#pragma unroll
            for (int k = 0; k < 6; ++k) insert6(s, o[k]);
        }
        const float eps = s[5];   // exact (k+1)-th smallest joint distance

        // nx: interior bins by prefix-diff + exact scan of boundary bins.
        int nx = 0;
        {
            int loB = binOf(xi - eps), hiB = binOf(xi + eps);
            int fLo = loB + 2, fHi = hiB - 2;
            if (fLo <= fHi) {
                if (l == 0) nx += pfx[fHi + 1] - pfx[fLo];
                int a0 = pfx[max(loB - 1, 0)], a1 = pfx[min(loB + 1, NBINS - 1) + 1];
                int b0 = pfx[max(hiB - 1, 0)], b1 = pfx[min(hiB + 1, NBINS - 1) + 1];
                for (int tt = a0 + l; tt < a1; tt += 16) nx += (fabsf(sxy[tt].x - xi) < eps);
                for (int tt = b0 + l; tt < b1; tt += 16) nx += (fabsf(sxy[tt].x - xi) < eps);
            } else {
                int a0 = pfx[max(loB - 1, 0)], a1 = pfx[min(hiB + 1, NBINS - 1) + 1];
                for (int tt = a0 + l; tt < a1; tt += 16) nx += (fabsf(sxy[tt].x - xi) < eps);
            }
        }
        // ny: same scheme on y-bucketed LDS array.
        int ny = 0;
        {
            int loB = binOf(yi - eps), hiB = binOf(yi + eps);
            int fLo = loB + 2, fHi = hiB - 2;
            if (fLo <= fHi) {
                if (l == 0) ny += pfy[fHi + 1] - pfy[fLo];
                int a0 = pfy[max(loB - 1, 0)], a1 = pfy[min(loB + 1, NBINS - 1) + 1];
                int b0 = pfy[max(hiB - 1, 0)], b1 = pfy[min(hiB + 1, NBINS - 1) + 1];
                for (int tt = a0 + l; tt < a1; tt += 16) ny += (fabsf(ys[tt] - yi) < eps);
                for (int tt = b0 + l; tt < b1; tt += 16) ny += (fabsf(ys[tt] - yi) < eps);
            } else {
                int a0 = pfy[max(loB - 1, 0)], a1 = pfy[min(hiB + 1, NBINS - 1) + 1];
                for (int tt = a0 + l; tt < a1; tt += 16) ny += (fabsf(ys[tt] - yi) < eps);
            }
        }

        int pk = (nx << 16) | ny;                 // totals <= 4096, no carry
#pragma unroll
        for (int m = 1; m < 16; m <<= 1) pk += __shfl_xor(pk, m);

        acc += digammaf_dev((float)(pk >> 16)) + digammaf_dev((float)(pk & 0xffff));
    }

    if (l == 0) red[wv * 4 + g] = acc;            // acc uniform within group
    __syncthreads();
    if (threadIdx.x == 0) {
        float v = 0.f;
#pragma unroll
        for (int k = 0; k < 16; ++k) v += red[k];
        (ws + WS_PART)[blockIdx.x] = v;
    }
}

// --------- Kernel 2: finalize ---------------------------------------------
__global__ void knnmi_final(const float* __restrict__ ws, float* __restrict__ out) {
    const float* partials = ws + WS_PART;
    const int w    = threadIdx.x >> 6;    // wave = channel
    const int lane = threadIdx.x & 63;
    float sum = 0.f;
#pragma unroll
    for (int i = lane; i < BLOCKS_PER_CH; i += 64)
        sum += partials[w * BLOCKS_PER_CH + i];
#pragma unroll
    for (int m = 32; m; m >>= 1) sum += __shfl_xor(sum, m);
    if (lane == 0) {
        float mi = digammaf_dev((float)KNN) + digammaf_dev((float)HW)
                 - sum / (float)HW;
        out[w] = fmaxf(mi, 0.f);
    }
}

extern "C" void kernel_launch(void* const* d_in, const int* in_sizes, int n_in,
                              void* d_out, int out_size, void* d_ws, size_t ws_size,
                              hipStream_t stream) {
    const float* x = (const float*)d_in[0];
    const float* y = (const float*)d_in[1];
    float* out = (float*)d_out;
    float* ws  = (float*)d_ws;   // all read regions fully rewritten every call

    knnmi_bucketize<<<2 * NCH, 1024, 0, stream>>>(x, y, ws);
    knnmi_rows<<<NBLOCKS, TPB, 0, stream>>>(ws);
    knnmi_final<<<1, NCH * 64, 0, stream>>>(ws, out);
}

// Round 10
// 42.662 us; speedup vs baseline: 1.6753x; 1.4879x over previous
//
#include <hip/hip_runtime.h>
#include <math.h>

#define HW 4096
#define NCH 4
#define TPB 1024                              // 16 waves/block, 1 row/wave
#define WPB 16
#define BLOCKS_PER_CH 256
#define NBLOCKS (NCH * BLOCKS_PER_CH)         // 1024
#define KNN 5

#define NBINS 512
#define BLO   (-6.0f)
#define BDELTA 0.0234375f      // 12/512, exact in fp32
#define BINV  (512.0f / 12.0f)
#define SLOP  1e-5f            // >> fp rounding of bin/edge math, << BDELTA
#define INFT  3.4e38f

// ws layout (float idx): bxx[4][4096]@0, bxy@16384, by@32768,
// prefX int@49152 (4*513), prefY after it, partials@57344 (1024 floats).
#define WS_BXY   16384
#define WS_BY    32768
#define WS_PREF  49152
#define WS_PART  57344

__device__ __forceinline__ int binOf(float v) {
    int b = (int)floorf((v - BLO) * BINV);
    return min(max(b, 0), NBINS - 1);
}

// digamma for positive integer args. Shift to >= 6 + asymptotic. ~1e-7.
__device__ __forceinline__ float digammaf_dev(float x) {
    float r = 0.f;
    while (x < 6.f) { r -= 1.f / x; x += 1.f; }
    float f = 1.f / x, f2 = f * f;
    return logf(x) - 0.5f * f
         - f2 * (1.f / 12.f - f2 * (1.f / 120.f - f2 * (1.f / 252.f))) + r;
}

// Insert d into ascending sorted 6-list (drop max): 6 independent med3.
__device__ __forceinline__ void insert6(float (&s)[6], float d) {
    float n0 = fminf(s[0], d);
    float n1 = __builtin_amdgcn_fmed3f(s[0], s[1], d);
    float n2 = __builtin_amdgcn_fmed3f(s[1], s[2], d);
    float n3 = __builtin_amdgcn_fmed3f(s[2], s[3], d);
    float n4 = __builtin_amdgcn_fmed3f(s[3], s[4], d);
    float n5 = __builtin_amdgcn_fmed3f(s[4], s[5], d);
    s[0] = n0; s[1] = n1; s[2] = n2; s[3] = n3; s[4] = n4; s[5] = n5;
}

// --------- Kernel 0: bucketize; 8 blocks = (channel x side) ---------------
__global__ __launch_bounds__(1024) void knnmi_bucketize(const float* __restrict__ x,
                                                        const float* __restrict__ y,
                                                        float* __restrict__ ws) {
    __shared__ int h[NBINS], tmp[NBINS], cur[NBINS];
    const int c    = blockIdx.x >> 1;
    const int side = blockIdx.x & 1;              // 0 = X pairs, 1 = Y values
    const int t    = threadIdx.x;
    const float* src = (side == 0 ? x : y) + c * HW;

    for (int i = t; i < NBINS; i += 1024) h[i] = 0;
    __syncthreads();
    for (int i = t; i < HW; i += 1024) atomicAdd(&h[binOf(src[i])], 1);
    __syncthreads();
    for (int off = 1; off < NBINS; off <<= 1) {
        for (int i = t; i < NBINS; i += 1024)
            tmp[i] = h[i] + ((i >= off) ? h[i - off] : 0);
        __syncthreads();
        for (int i = t; i < NBINS; i += 1024) h[i] = tmp[i];
        __syncthreads();
    }
    int* pref = (int*)ws + WS_PREF + (side ? NCH * (NBINS + 1) : 0) + c * (NBINS + 1);
    for (int i = t; i < NBINS; i += 1024) {
        int e = i ? h[i - 1] : 0;
        pref[i] = e;
        cur[i] = e;
    }
    if (t == 0) pref[NBINS] = h[NBINS - 1];
    __syncthreads();
    if (side == 0) {
        const float* yc = y + c * HW;
        float* bxx = ws + c * HW;
        float* bxy = ws + WS_BXY + c * HW;
        for (int i = t; i < HW; i += 1024) {
            float xv = src[i];
            int pos = atomicAdd(&cur[binOf(xv)], 1);
            bxx[pos] = xv;
            bxy[pos] = yc[i];
        }
    } else {
        float* by = ws + WS_BY + c * HW;
        for (int i = t; i < HW; i += 1024) {
            float yv = src[i];
            int pos = atomicAdd(&cur[binOf(yv)], 1);
            by[pos] = yv;
        }
    }
}

// --------- Kernel 1: one row per wave; fixed window + rare adaptive -------
__global__ __launch_bounds__(TPB, 8) void knnmi_rows(float* __restrict__ ws) {
    __shared__ float2 sxy[HW];            // 32 KB x-bucketed {x,y}
    __shared__ float  ys[HW];             // 16 KB y-bucketed values
    __shared__ int pfx[NBINS + 1], pfy[NBINS + 1];
    __shared__ float red[WPB];

    const int c  = blockIdx.x >> 8;       // channel
    const int rb = blockIdx.x & 255;      // block within channel
    const float* bxx = ws + c * HW;
    const float* bxy = ws + WS_BXY + c * HW;
    const float* by  = ws + WS_BY  + c * HW;
    const int* prefx = (const int*)ws + WS_PREF + c * (NBINS + 1);
    const int* prefy = (const int*)ws + WS_PREF + NCH * (NBINS + 1) + c * (NBINS + 1);

    {   // staging: HW/4 == TPB, exactly one float4-pair per thread
        int i = threadIdx.x;
        float4 xv = ((const float4*)bxx)[i];
        float4 yv = ((const float4*)bxy)[i];
        ((float4*)sxy)[2 * i]     = make_float4(xv.x, yv.x, xv.y, yv.y);
        ((float4*)sxy)[2 * i + 1] = make_float4(xv.z, yv.z, xv.w, yv.w);
        ((float4*)ys)[i] = ((const float4*)by)[i];
        if (i <= NBINS) { pfx[i] = prefx[i]; pfy[i] = prefy[i]; }
    }
    __syncthreads();

    const int wv   = threadIdx.x >> 6;    // wave = row
    const int lane = threadIdx.x & 63;
    const int p    = rb + 256 * wv;       // stratified row index

    const float xi = sxy[p].x;
    const float yi = sxy[p].y;

    float s[6];
#pragma unroll
    for (int q = 0; q < 6; ++q) s[q] = INFT;

    // Fixed window [p-128, p+128): 4 unrolled masked 64-lane chunks.
    // Includes self (d = 0). Pure ILP, no checks inside.
    int wL = p - 128, wR = p + 128;
#pragma unroll
    for (int ch = 0; ch < 4; ++ch) {
        int idx = wL + (ch << 6) + lane;
        bool v = (idx >= 0) && (idx < HW);
        float2 pp = sxy[v ? idx : p];
        float d = v ? fmaxf(fabsf(xi - pp.x), fabsf(yi - pp.y)) : INFT;
        insert6(s, d);
    }
    wL = max(wL, 0); wR = min(wR, HW);
    bool lD = (wL == 0), rD = (wR == HW);

    // Check + rare adaptive expansion (64 candidates/side/iter).
    for (int it = 0; it < 80; ++it) {
        // Conservative lower bounds on any unscanned fl|dx| per side.
        float eL = INFT, eR = INFT;
        if (!lD) {
            int b = binOf(sxy[wL - 1].x);
            eL = xi - (BLO + (float)(b + 1) * BDELTA + SLOP);
        }
        if (!rD) {
            int b = binOf(sxy[wR].x);
            eR = (BLO + (float)b * BDELTA - SLOP) - xi;
        }
        // Exact: >=6 retained values <= edge  <=>  merged s[5] <= edge.
        int cl = 0, cr = 0;
#pragma unroll
        for (int q = 0; q < 6; ++q) { cl += (s[q] <= eL); cr += (s[q] <= eR); }
        int pk2 = cl | (cr << 16);
#pragma unroll
        for (int m = 1; m < 64; m <<= 1) pk2 += __shfl_xor(pk2, m);
        lD = lD || ((pk2 & 0xffff) >= 6);
        rD = rD || ((pk2 >> 16) >= 6);
        if (lD && rD) break;                 // wave-uniform
        if (!lD) {
            int idx = wL - 64 + lane;
            bool v = (idx >= 0);
            float2 pp = sxy[v ? idx : p];
            insert6(s, v ? fmaxf(fabsf(xi - pp.x), fabsf(yi - pp.y)) : INFT);
            wL = max(wL - 64, 0);
            lD = (wL == 0);
        }
        if (!rD) {
            int idx = wR + lane;
            bool v = (idx < HW);
            float2 pp = sxy[v ? idx : p];
            insert6(s, v ? fmaxf(fabsf(xi - pp.x), fabsf(yi - pp.y)) : INFT);
            wR = min(wR + 64, HW);
            rD = (wR == HW);
        }
    }

    // Merge 64 per-lane sorted 6-lists (6 butterfly stages).
#pragma unroll
    for (int m = 1; m < 64; m <<= 1) {
        float o[6];
#pragma unroll
        for (int q = 0; q < 6; ++q) o[q] = __shfl_xor(s[q], m);
#pragma unroll
        for (int q = 0; q < 6; ++q) insert6(s, o[q]);
    }
    const float eps = s[5];   // exact (k+1)-th smallest joint distance

    // nx: interior bins by prefix-diff + exact scan of boundary bins.
    int nx = 0;
    {
        int loB = binOf(xi - eps), hiB = binOf(xi + eps);
        int fLo = loB + 2, fHi = hiB - 2;
        if (fLo <= fHi) {
            if (lane == 0) nx += pfx[fHi + 1] - pfx[fLo];
            int a0 = pfx[max(loB - 1, 0)], a1 = pfx[min(loB + 1, NBINS - 1) + 1];
            int b0 = pfx[max(hiB - 1, 0)], b1 = pfx[min(hiB + 1, NBINS - 1) + 1];
            for (int tt = a0 + lane; tt < a1; tt += 64) nx += (fabsf(sxy[tt].x - xi) < eps);
            for (int tt = b0 + lane; tt < b1; tt += 64) nx += (fabsf(sxy[tt].x - xi) < eps);
        } else {
            int a0 = pfx[max(loB - 1, 0)], a1 = pfx[min(hiB + 1, NBINS - 1) + 1];
            for (int tt = a0 + lane; tt < a1; tt += 64) nx += (fabsf(sxy[tt].x - xi) < eps);
        }
    }
    // ny: same scheme on y-bucketed LDS array.
    int ny = 0;
    {
        int loB = binOf(yi - eps), hiB = binOf(yi + eps);
        int fLo = loB + 2, fHi = hiB - 2;
        if (fLo <= fHi) {
            if (lane == 0) ny += pfy[fHi + 1] - pfy[fLo];
            int a0 = pfy[max(loB - 1, 0)], a1 = pfy[min(loB + 1, NBINS - 1) + 1];
            int b0 = pfy[max(hiB - 1, 0)], b1 = pfy[min(hiB + 1, NBINS - 1) + 1];
            for (int tt = a0 + lane; tt < a1; tt += 64) ny += (fabsf(ys[tt] - yi) < eps);
            for (int tt = b0 + lane; tt < b1; tt += 64) ny += (fabsf(ys[tt] - yi) < eps);
        } else {
            int a0 = pfy[max(loB - 1, 0)], a1 = pfy[min(hiB + 1, NBINS - 1) + 1];
            for (int tt = a0 + lane; tt < a1; tt += 64) ny += (fabsf(ys[tt] - yi) < eps);
        }
    }

    int pk = (nx << 16) | ny;                 // totals <= 4096, no carry
#pragma unroll
    for (int m = 1; m < 64; m <<= 1) pk += __shfl_xor(pk, m);

    if (lane == 0)
        red[wv] = digammaf_dev((float)(pk >> 16)) + digammaf_dev((float)(pk & 0xffff));
    __syncthreads();

    if (threadIdx.x == 0) {
        float v = 0.f;
#pragma unroll
        for (int k = 0; k < WPB; ++k) v += red[k];
        (ws + WS_PART)[blockIdx.x] = v;
    }
}

// --------- Kernel 2: finalize ---------------------------------------------
__global__ void knnmi_final(const float* __restrict__ ws, float* __restrict__ out) {
    const float* partials = ws + WS_PART;
    const int w    = threadIdx.x >> 6;    // wave = channel
    const int lane = threadIdx.x & 63;
    float sum = 0.f;
#pragma unroll
    for (int i = lane; i < BLOCKS_PER_CH; i += 64)
        sum += partials[w * BLOCKS_PER_CH + i];
#pragma unroll
    for (int m = 32; m; m >>= 1) sum += __shfl_xor(sum, m);
    if (lane == 0) {
        float mi = digammaf_dev((float)KNN) + digammaf_dev((float)HW)
                 - sum / (float)HW;
        out[w] = fmaxf(mi, 0.f);
    }
}

extern "C" void kernel_launch(void* const* d_in, const int* in_sizes, int n_in,
                              void* d_out, int out_size, void* d_ws, size_t ws_size,
                              hipStream_t stream) {
    const float* x = (const float*)d_in[0];
    const float* y = (const float*)d_in[1];
    float* out = (float*)d_out;
    float* ws  = (float*)d_ws;   // all read regions fully rewritten every call

    knnmi_bucketize<<<2 * NCH, 1024, 0, stream>>>(x, y, ws);
    knnmi_rows<<<NBLOCKS, TPB, 0, stream>>>(ws);
    knnmi_final<<<1, NCH * 64, 0, stream>>>(ws, out);
}

// Round 11
// 33.011 us; speedup vs baseline: 2.1651x; 1.2923x over previous
//
#include <hip/hip_runtime.h>
#include <math.h>

#define HW 4096
#define NCH 4
#define TPB 256                               // 4 waves/block
#define ROWS_PER_BLOCK 16                     // 4 waves x 4 rows (G=16)
#define BLOCKS_PER_CH 256
#define NBLOCKS (NCH * BLOCKS_PER_CH)         // 1024
#define KNN 5
#define WIN 512                               // fixed scan window (ranks)

#define NBINS 512
#define BLO   (-6.0f)
#define BDELTA 0.0234375f      // 12/512, exact in fp32
#define BINV  (512.0f / 12.0f)
#define SLOP  1e-5f            // >> fp rounding of bin/edge math, << BDELTA
#define INFT  3.4e38f

// ws layout (float idx): bxx[4][4096]@0, bxy@16384, by@32768,
// prefX int@49152 (4*513), prefY after it, partials@57344 (1024 floats).
#define WS_BXY   16384
#define WS_BY    32768
#define WS_PREF  49152
#define WS_PART  57344

__device__ __forceinline__ int binOf(float v) {
    int b = (int)floorf((v - BLO) * BINV);
    return min(max(b, 0), NBINS - 1);
}

// digamma for positive integer args. Shift to >= 6 + asymptotic. ~1e-7.
__device__ __forceinline__ float digammaf_dev(float x) {
    float r = 0.f;
    while (x < 6.f) { r -= 1.f / x; x += 1.f; }
    float f = 1.f / x, f2 = f * f;
    return logf(x) - 0.5f * f
         - f2 * (1.f / 12.f - f2 * (1.f / 120.f - f2 * (1.f / 252.f))) + r;
}

// Insert d into ascending sorted 6-list (drop max): 6 independent med3.
__device__ __forceinline__ void insert6(float (&s)[6], float d) {
    float n0 = fminf(s[0], d);
    float n1 = __builtin_amdgcn_fmed3f(s[0], s[1], d);
    float n2 = __builtin_amdgcn_fmed3f(s[1], s[2], d);
    float n3 = __builtin_amdgcn_fmed3f(s[2], s[3], d);
    float n4 = __builtin_amdgcn_fmed3f(s[3], s[4], d);
    float n5 = __builtin_amdgcn_fmed3f(s[4], s[5], d);
    s[0] = n0; s[1] = n1; s[2] = n2; s[3] = n3; s[4] = n4; s[5] = n5;
}

// --------- Kernel 0: bucketize; 8 blocks = (channel x side) ---------------
__global__ __launch_bounds__(1024) void knnmi_bucketize(const float* __restrict__ x,
                                                        const float* __restrict__ y,
                                                        float* __restrict__ ws) {
    __shared__ int h[NBINS], tmp[NBINS], cur[NBINS];
    const int c    = blockIdx.x >> 1;
    const int side = blockIdx.x & 1;              // 0 = X pairs, 1 = Y values
    const int t    = threadIdx.x;
    const float* src = (side == 0 ? x : y) + c * HW;

    for (int i = t; i < NBINS; i += 1024) h[i] = 0;
    __syncthreads();
    for (int i = t; i < HW; i += 1024) atomicAdd(&h[binOf(src[i])], 1);
    __syncthreads();
    for (int off = 1; off < NBINS; off <<= 1) {
        for (int i = t; i < NBINS; i += 1024)
            tmp[i] = h[i] + ((i >= off) ? h[i - off] : 0);
        __syncthreads();
        for (int i = t; i < NBINS; i += 1024) h[i] = tmp[i];
        __syncthreads();
    }
    int* pref = (int*)ws + WS_PREF + (side ? NCH * (NBINS + 1) : 0) + c * (NBINS + 1);
    for (int i = t; i < NBINS; i += 1024) {
        int e = i ? h[i - 1] : 0;
        pref[i] = e;
        cur[i] = e;
    }
    if (t == 0) pref[NBINS] = h[NBINS - 1];
    __syncthreads();
    if (side == 0) {
        const float* yc = y + c * HW;
        float* bxx = ws + c * HW;
        float* bxy = ws + WS_BXY + c * HW;
        for (int i = t; i < HW; i += 1024) {
            float xv = src[i];
            int pos = atomicAdd(&cur[binOf(xv)], 1);
            bxx[pos] = xv;
            bxy[pos] = yc[i];
        }
    } else {
        float* by = ws + WS_BY + c * HW;
        for (int i = t; i < HW; i += 1024) {
            float yv = src[i];
            int pos = atomicAdd(&cur[binOf(yv)], 1);
            by[pos] = yv;
        }
    }
}

// --------- Kernel 1: fixed window + post-merge check + rare brute fallback -
__global__ __launch_bounds__(TPB) void knnmi_rows(float* __restrict__ ws) {
    __shared__ float2 sxy[HW];            // 32 KB x-bucketed {x,y}
    __shared__ float  ys[HW];             // 16 KB y-bucketed values
    __shared__ int pfx[NBINS + 1], pfy[NBINS + 1];
    __shared__ float red[ROWS_PER_BLOCK];

    const int c  = blockIdx.x >> 8;       // channel
    const int rb = blockIdx.x & 255;      // block within channel
    const float* bxx = ws + c * HW;
    const float* bxy = ws + WS_BXY + c * HW;
    const float* by  = ws + WS_BY  + c * HW;
    const int* prefx = (const int*)ws + WS_PREF + c * (NBINS + 1);
    const int* prefy = (const int*)ws + WS_PREF + NCH * (NBINS + 1) + c * (NBINS + 1);

    for (int i = threadIdx.x; i < HW / 4; i += TPB) {
        float4 xv = ((const float4*)bxx)[i];
        float4 yv = ((const float4*)bxy)[i];
        ((float4*)sxy)[2 * i]     = make_float4(xv.x, yv.x, xv.y, yv.y);
        ((float4*)sxy)[2 * i + 1] = make_float4(xv.z, yv.z, xv.w, yv.w);
        ((float4*)ys)[i] = ((const float4*)by)[i];
    }
    for (int i = threadIdx.x; i <= NBINS; i += TPB) {
        pfx[i] = prefx[i];
        pfy[i] = prefy[i];
    }
    __syncthreads();

    const int wv   = threadIdx.x >> 6;    // wave 0..3
    const int lane = threadIdx.x & 63;
    const int l    = lane & 15;           // lane within 16-lane group
    const int g    = lane >> 4;           // group (row) within wave
    const int q    = wv * 4 + g;          // 0..15
    const int p    = rb + 256 * q;        // stratified row index

    const float xi = sxy[p].x;
    const float yi = sxy[p].y;

    // Fixed 512-rank window around p (clamped, even-aligned, contains p).
    int lo = p - WIN / 2;
    lo = max(lo, 0); lo = min(lo, HW - WIN); lo &= ~1;
    const int hi = lo + WIN;
    const float4* f4 = (const float4*)sxy;
    const int fbase = lo >> 1;

    float s[6];
#pragma unroll
    for (int k = 0; k < 6; ++k) s[k] = INFT;

    // 16 iters x ds_read_b128 (2 candidates); includes self (d=0).
#pragma unroll 8
    for (int it = 0; it < WIN / 32; ++it) {
        float4 pp = f4[fbase + it * 16 + l];
        insert6(s, fmaxf(fabsf(xi - pp.x), fabsf(yi - pp.y)));
        insert6(s, fmaxf(fabsf(xi - pp.z), fabsf(yi - pp.w)));
    }

    // Merge 16 per-lane sorted 6-lists (4 butterfly stages, all 4 groups
    // ride the same wave-wide shuffles).
#pragma unroll
    for (int m = 1; m < 16; m <<= 1) {
        float o[6];
#pragma unroll
        for (int k = 0; k < 6; ++k) o[k] = __shfl_xor(s[k], m);
#pragma unroll
        for (int k = 0; k < 6; ++k) insert6(s, o[k]);
    }
    float eps = s[5];    // candidate (k+1)-th smallest (window-local)

    // ONE post-merge exactness check: any unscanned j has
    // fl|xi-xj| >= bin-edge bound (bucket order => bin(x_j) bounded).
    float eL = INFT, eR = INFT;
    if (lo > 0) {
        int b = binOf(sxy[lo - 1].x);
        eL = xi - (BLO + (float)(b + 1) * BDELTA + SLOP);
    }
    if (hi < HW) {
        int b = binOf(sxy[hi].x);
        eR = (BLO + (float)b * BDELTA - SLOP) - xi;
    }
    const bool ok = (eps <= eL) && (eps <= eR);

    // Rare fallback (~5% rows): whole-wave exact brute scan of all 4096.
    unsigned long long bad = __ballot((l == 0) && !ok);
    while (bad) {
        int bit = (int)__ffsll((unsigned long long)bad) - 1;
        bad &= bad - 1;
        const int tg = bit >> 4;                      // failed group in wave
        const int pt = rb + 256 * (wv * 4 + tg);
        const float xt = sxy[pt].x, yt = sxy[pt].y;
        float s3[6];
#pragma unroll
        for (int k = 0; k < 6; ++k) s3[k] = INFT;
#pragma unroll 8
        for (int it = 0; it < HW / 128; ++it) {       // 32 iters, G=64
            float4 pp = f4[it * 64 + lane];
            insert6(s3, fmaxf(fabsf(xt - pp.x), fabsf(yt - pp.y)));
            insert6(s3, fmaxf(fabsf(xt - pp.z), fabsf(yt - pp.w)));
        }
#pragma unroll
        for (int m = 1; m < 64; m <<= 1) {
            float o[6];
#pragma unroll
            for (int k = 0; k < 6; ++k) o[k] = __shfl_xor(s3[k], m);
#pragma unroll
            for (int k = 0; k < 6; ++k) insert6(s3, o[k]);
        }
        if (g == tg) eps = s3[5];                     // exact global 6th
    }

    // nx: interior bins by prefix-diff + exact scan of boundary bins.
    int nx = 0;
    {
        int loB = binOf(xi - eps), hiB = binOf(xi + eps);
        int fLo = loB + 2, fHi = hiB - 2;
        if (fLo <= fHi) {
            if (l == 0) nx += pfx[fHi + 1] - pfx[fLo];
            int a0 = pfx[max(loB - 1, 0)], a1 = pfx[min(loB + 1, NBINS - 1) + 1];
            int b0 = pfx[max(hiB - 1, 0)], b1 = pfx[min(hiB + 1, NBINS - 1) + 1];
            for (int tt = a0 + l; tt < a1; tt += 16) nx += (fabsf(sxy[tt].x - xi) < eps);
            for (int tt = b0 + l; tt < b1; tt += 16) nx += (fabsf(sxy[tt].x - xi) < eps);
        } else {
            int a0 = pfx[max(loB - 1, 0)], a1 = pfx[min(hiB + 1, NBINS - 1) + 1];
            for (int tt = a0 + l; tt < a1; tt += 16) nx += (fabsf(sxy[tt].x - xi) < eps);
        }
    }
    // ny: same scheme on y-bucketed LDS array.
    int ny = 0;
    {
        int loB = binOf(yi - eps), hiB = binOf(yi + eps);
        int fLo = loB + 2, fHi = hiB - 2;
        if (fLo <= fHi) {
            if (l == 0) ny += pfy[fHi + 1] - pfy[fLo];
            int a0 = pfy[max(loB - 1, 0)], a1 = pfy[min(loB + 1, NBINS - 1) + 1];
            int b0 = pfy[max(hiB - 1, 0)], b1 = pfy[min(hiB + 1, NBINS - 1) + 1];
            for (int tt = a0 + l; tt < a1; tt += 16) ny += (fabsf(ys[tt] - yi) < eps);
            for (int tt = b0 + l; tt < b1; tt += 16) ny += (fabsf(ys[tt] - yi) < eps);
        } else {
            int a0 = pfy[max(loB - 1, 0)], a1 = pfy[min(hiB + 1, NBINS - 1) + 1];
            for (int tt = a0 + l; tt < a1; tt += 16) ny += (fabsf(ys[tt] - yi) < eps);
        }
    }

    int pk = (nx << 16) | ny;                 // totals <= 4096, no carry
#pragma unroll
    for (int m = 1; m < 16; m <<= 1) pk += __shfl_xor(pk, m);

    if (l == 0)
        red[q] = digammaf_dev((float)(pk >> 16)) + digammaf_dev((float)(pk & 0xffff));
    __syncthreads();

    if (threadIdx.x == 0) {
        float v = 0.f;
#pragma unroll
        for (int k = 0; k < ROWS_PER_BLOCK; ++k) v += red[k];
        (ws + WS_PART)[blockIdx.x] = v;
    }
}

// --------- Kernel 2: finalize ---------------------------------------------
__global__ void knnmi_final(const float* __restrict__ ws, float* __restrict__ out) {
    const float* partials = ws + WS_PART;
    const int w    = threadIdx.x >> 6;    // wave = channel
    const int lane = threadIdx.x & 63;
    float sum = 0.f;
#pragma unroll
    for (int i = lane; i < BLOCKS_PER_CH; i += 64)
        sum += partials[w * BLOCKS_PER_CH + i];
#pragma unroll
    for (int m = 32; m; m >>= 1) sum += __shfl_xor(sum, m);
    if (lane == 0) {
        float mi = digammaf_dev((float)KNN) + digammaf_dev((float)HW)
                 - sum / (float)HW;
        out[w] = fmaxf(mi, 0.f);
    }
}

extern "C" void kernel_launch(void* const* d_in, const int* in_sizes, int n_in,
                              void* d_out, int out_size, void* d_ws, size_t ws_size,
                              hipStream_t stream) {
    const float* x = (const float*)d_in[0];
    const float* y = (const float*)d_in[1];
    float* out = (float*)d_out;
    float* ws  = (float*)d_ws;   // all read regions fully rewritten every call

    knnmi_bucketize<<<2 * NCH, 1024, 0, stream>>>(x, y, ws);
    knnmi_rows<<<NBLOCKS, TPB, 0, stream>>>(ws);
    knnmi_final<<<1, NCH * 64, 0, stream>>>(ws, out);
}

// Round 12
// 32.839 us; speedup vs baseline: 2.1764x; 1.0052x over previous
//
#include <hip/hip_runtime.h>
#include <math.h>

#define HW 4096
#define NCH 4
#define TPB 256                               // 4 waves/block
#define ROWS_PER_BLOCK 16                     // 4 waves x 4 rows (G=16)
#define BLOCKS_PER_CH 256
#define NBLOCKS (NCH * BLOCKS_PER_CH)         // 1024
#define KNN 5
#define WIN 512                               // fixed scan window (ranks)

#define NBINS 512
#define BLO   (-6.0f)
#define BDELTA 0.0234375f      // 12/512, exact in fp32
#define BINV  (512.0f / 12.0f)
#define SLOP  1e-5f            // >> fp rounding of bin/edge math, << BDELTA
#define INFT  3.4e38f

// ws layout (float idx): bxx[4][4096]@0, bxy@16384, by@32768,
// prefX int@49152 (4*513), prefY after it, partials@57344 (1024 floats).
#define WS_BXY   16384
#define WS_BY    32768
#define WS_PREF  49152
#define WS_PART  57344

__device__ __forceinline__ int binOf(float v) {
    int b = (int)floorf((v - BLO) * BINV);
    return min(max(b, 0), NBINS - 1);
}

// digamma for positive integer args. Shift to >= 6 + asymptotic. ~1e-7.
__device__ __forceinline__ float digammaf_dev(float x) {
    float r = 0.f;
    while (x < 6.f) { r -= 1.f / x; x += 1.f; }
    float f = 1.f / x, f2 = f * f;
    return logf(x) - 0.5f * f
         - f2 * (1.f / 12.f - f2 * (1.f / 120.f - f2 * (1.f / 252.f))) + r;
}

// Insert d into ascending sorted 6-list (drop max): 6 independent med3.
__device__ __forceinline__ void insert6(float (&s)[6], float d) {
    float n0 = fminf(s[0], d);
    float n1 = __builtin_amdgcn_fmed3f(s[0], s[1], d);
    float n2 = __builtin_amdgcn_fmed3f(s[1], s[2], d);
    float n3 = __builtin_amdgcn_fmed3f(s[2], s[3], d);
    float n4 = __builtin_amdgcn_fmed3f(s[3], s[4], d);
    float n5 = __builtin_amdgcn_fmed3f(s[4], s[5], d);
    s[0] = n0; s[1] = n1; s[2] = n2; s[3] = n3; s[4] = n4; s[5] = n5;
}

// --------- Kernel 0: bucketize; 8 blocks = (channel x side) ----------------
// 256 threads, values in registers, single-wave shuffle scan (no barrier
// storm -- the 1024-thread 18-barrier version cost ~15 us).
__global__ __launch_bounds__(256) void knnmi_bucketize(const float* __restrict__ x,
                                                       const float* __restrict__ y,
                                                       float* __restrict__ ws) {
    __shared__ int h[NBINS];          // histogram, then exclusive starts
    const int c    = blockIdx.x >> 1;
    const int side = blockIdx.x & 1;  // 0 = X pairs, 1 = Y values
    const int t    = threadIdx.x;
    const float* src  = (side == 0 ? x : y) + c * HW;
    const float* ysrc = y + c * HW;
    int* pref = (int*)ws + WS_PREF + (side ? NCH * (NBINS + 1) : 0) + c * (NBINS + 1);

    for (int i = t; i < NBINS; i += 256) h[i] = 0;
    __syncthreads();

    float vx[16], vy[16];
    int bn[16];
#pragma unroll
    for (int k = 0; k < 16; ++k) {            // one read pass, regs hold all
        int i = t + k * 256;
        float v = src[i];
        vx[k] = v;
        vy[k] = (side == 0) ? ysrc[i] : 0.f;  // y-side: unused, DCE'd
        bn[k] = binOf(v);
        atomicAdd(&h[bn[k]], 1);
    }
    __syncthreads();

    if (t < 64) {                             // single-wave scan, no barriers
        int sinc[8];
        {
            int c0 = h[t * 8 + 0];
            sinc[0] = c0;
#pragma unroll
            for (int j = 1; j < 8; ++j) sinc[j] = sinc[j - 1] + h[t * 8 + j];
        }
        int tot = sinc[7], inc = tot;
#pragma unroll
        for (int off = 1; off < 64; off <<= 1) {
            int u = __shfl_up(inc, off);
            if (t >= off) inc += u;
        }
        int ex = inc - tot;                   // exclusive prefix across lanes
#pragma unroll
        for (int j = 0; j < 8; ++j) {
            int st = ex + (j ? sinc[j - 1] : 0);
            h[t * 8 + j]    = st;             // in-place: own bins only
            pref[t * 8 + j] = st;
        }
        if (t == 63) pref[NBINS] = HW;
    }
    __syncthreads();

    if (side == 0) {
        float* bxx = ws + c * HW;
        float* bxy = ws + WS_BXY + c * HW;
#pragma unroll
        for (int k = 0; k < 16; ++k) {
            int pos = atomicAdd(&h[bn[k]], 1);
            bxx[pos] = vx[k];
            bxy[pos] = vy[k];
        }
    } else {
        float* by = ws + WS_BY + c * HW;
#pragma unroll
        for (int k = 0; k < 16; ++k) {
            int pos = atomicAdd(&h[bn[k]], 1);
            by[pos] = vx[k];
        }
    }
}

// --------- Kernel 1: fixed window + post-merge check + rare brute fallback -
__global__ __launch_bounds__(TPB) void knnmi_rows(float* __restrict__ ws) {
    __shared__ float2 sxy[HW];            // 32 KB x-bucketed {x,y}
    __shared__ float  ys[HW];             // 16 KB y-bucketed values
    __shared__ int pfx[NBINS + 1], pfy[NBINS + 1];
    __shared__ float red[ROWS_PER_BLOCK];

    const int c  = blockIdx.x >> 8;       // channel
    const int rb = blockIdx.x & 255;      // block within channel
    const float* bxx = ws + c * HW;
    const float* bxy = ws + WS_BXY + c * HW;
    const float* by  = ws + WS_BY  + c * HW;
    const int* prefx = (const int*)ws + WS_PREF + c * (NBINS + 1);
    const int* prefy = (const int*)ws + WS_PREF + NCH * (NBINS + 1) + c * (NBINS + 1);

    for (int i = threadIdx.x; i < HW / 4; i += TPB) {
        float4 xv = ((const float4*)bxx)[i];
        float4 yv = ((const float4*)bxy)[i];
        ((float4*)sxy)[2 * i]     = make_float4(xv.x, yv.x, xv.y, yv.y);
        ((float4*)sxy)[2 * i + 1] = make_float4(xv.z, yv.z, xv.w, yv.w);
        ((float4*)ys)[i] = ((const float4*)by)[i];
    }
    for (int i = threadIdx.x; i <= NBINS; i += TPB) {
        pfx[i] = prefx[i];
        pfy[i] = prefy[i];
    }
    __syncthreads();

    const int wv   = threadIdx.x >> 6;    // wave 0..3
    const int lane = threadIdx.x & 63;
    const int l    = lane & 15;           // lane within 16-lane group
    const int g    = lane >> 4;           // group (row) within wave
    const int q    = wv * 4 + g;          // 0..15
    const int p    = rb + 256 * q;        // stratified row index

    const float xi = sxy[p].x;
    const float yi = sxy[p].y;

    // Fixed 512-rank window around p (clamped, even-aligned, contains p).
    int lo = p - WIN / 2;
    lo = max(lo, 0); lo = min(lo, HW - WIN); lo &= ~1;
    const int hi = lo + WIN;
    const float4* f4 = (const float4*)sxy;
    const int fbase = lo >> 1;

    float s[6];
#pragma unroll
    for (int k = 0; k < 6; ++k) s[k] = INFT;

    // 16 iters x ds_read_b128 (2 candidates); includes self (d=0).
#pragma unroll 8
    for (int it = 0; it < WIN / 32; ++it) {
        float4 pp = f4[fbase + it * 16 + l];
        insert6(s, fmaxf(fabsf(xi - pp.x), fabsf(yi - pp.y)));
        insert6(s, fmaxf(fabsf(xi - pp.z), fabsf(yi - pp.w)));
    }

    // Merge 16 per-lane sorted 6-lists (4 butterfly stages, all 4 groups
    // ride the same wave-wide shuffles).
#pragma unroll
    for (int m = 1; m < 16; m <<= 1) {
        float o[6];
#pragma unroll
        for (int k = 0; k < 6; ++k) o[k] = __shfl_xor(s[k], m);
#pragma unroll
        for (int k = 0; k < 6; ++k) insert6(s, o[k]);
    }
    float eps = s[5];    // candidate (k+1)-th smallest (window-local)

    // ONE post-merge exactness check: any unscanned j has
    // fl|xi-xj| >= bin-edge bound (bucket order => bin(x_j) bounded).
    float eL = INFT, eR = INFT;
    if (lo > 0) {
        int b = binOf(sxy[lo - 1].x);
        eL = xi - (BLO + (float)(b + 1) * BDELTA + SLOP);
    }
    if (hi < HW) {
        int b = binOf(sxy[hi].x);
        eR = (BLO + (float)b * BDELTA - SLOP) - xi;
    }
    const bool ok = (eps <= eL) && (eps <= eR);

    // Rare fallback (~5% rows): whole-wave exact brute scan of all 4096.
    unsigned long long bad = __ballot((l == 0) && !ok);
    while (bad) {
        int bit = (int)__ffsll((unsigned long long)bad) - 1;
        bad &= bad - 1;
        const int tg = bit >> 4;                      // failed group in wave
        const int pt = rb + 256 * (wv * 4 + tg);
        const float xt = sxy[pt].x, yt = sxy[pt].y;
        float s3[6];
#pragma unroll
        for (int k = 0; k < 6; ++k) s3[k] = INFT;
#pragma unroll 8
        for (int it = 0; it < HW / 128; ++it) {       // 32 iters, G=64
            float4 pp = f4[it * 64 + lane];
            insert6(s3, fmaxf(fabsf(xt - pp.x), fabsf(yt - pp.y)));
            insert6(s3, fmaxf(fabsf(xt - pp.z), fabsf(yt - pp.w)));
        }
#pragma unroll
        for (int m = 1; m < 64; m <<= 1) {
            float o[6];
#pragma unroll
            for (int k = 0; k < 6; ++k) o[k] = __shfl_xor(s3[k], m);
#pragma unroll
            for (int k = 0; k < 6; ++k) insert6(s3, o[k]);
        }
        if (g == tg) eps = s3[5];                     // exact global 6th
    }

    // nx: interior bins by prefix-diff + exact scan of boundary bins.
    int nx = 0;
    {
        int loB = binOf(xi - eps), hiB = binOf(xi + eps);
        int fLo = loB + 2, fHi = hiB - 2;
        if (fLo <= fHi) {
            if (l == 0) nx += pfx[fHi + 1] - pfx[fLo];
            int a0 = pfx[max(loB - 1, 0)], a1 = pfx[min(loB + 1, NBINS - 1) + 1];
            int b0 = pfx[max(hiB - 1, 0)], b1 = pfx[min(hiB + 1, NBINS - 1) + 1];
            for (int tt = a0 + l; tt < a1; tt += 16) nx += (fabsf(sxy[tt].x - xi) < eps);
            for (int tt = b0 + l; tt < b1; tt += 16) nx += (fabsf(sxy[tt].x - xi) < eps);
        } else {
            int a0 = pfx[max(loB - 1, 0)], a1 = pfx[min(hiB + 1, NBINS - 1) + 1];
            for (int tt = a0 + l; tt < a1; tt += 16) nx += (fabsf(sxy[tt].x - xi) < eps);
        }
    }
    // ny: same scheme on y-bucketed LDS array.
    int ny = 0;
    {
        int loB = binOf(yi - eps), hiB = binOf(yi + eps);
        int fLo = loB + 2, fHi = hiB - 2;
        if (fLo <= fHi) {
            if (l == 0) ny += pfy[fHi + 1] - pfy[fLo];
            int a0 = pfy[max(loB - 1, 0)], a1 = pfy[min(loB + 1, NBINS - 1) + 1];
            int b0 = pfy[max(hiB - 1, 0)], b1 = pfy[min(hiB + 1, NBINS - 1) + 1];
            for (int tt = a0 + l; tt < a1; tt += 16) ny += (fabsf(ys[tt] - yi) < eps);
            for (int tt = b0 + l; tt < b1; tt += 16) ny += (fabsf(ys[tt] - yi) < eps);
        } else {
            int a0 = pfy[max(loB - 1, 0)], a1 = pfy[min(hiB + 1, NBINS - 1) + 1];
            for (int tt = a0 + l; tt < a1; tt += 16) ny += (fabsf(ys[tt] - yi) < eps);
        }
    }

    int pk = (nx << 16) | ny;                 // totals <= 4096, no carry
#pragma unroll
    for (int m = 1; m < 16; m <<= 1) pk += __shfl_xor(pk, m);

    if (l == 0)
        red[q] = digammaf_dev((float)(pk >> 16)) + digammaf_dev((float)(pk & 0xffff));
    __syncthreads();

    if (threadIdx.x == 0) {
        float v = 0.f;
#pragma unroll
        for (int k = 0; k < ROWS_PER_BLOCK; ++k) v += red[k];
        (ws + WS_PART)[blockIdx.x] = v;
    }
}

// --------- Kernel 2: finalize ---------------------------------------------
__global__ void knnmi_final(const float* __restrict__ ws, float* __restrict__ out) {
    const float* partials = ws + WS_PART;
    const int w    = threadIdx.x >> 6;    // wave = channel
    const int lane = threadIdx.x & 63;
    float sum = 0.f;
#pragma unroll
    for (int i = lane; i < BLOCKS_PER_CH; i += 64)
        sum += partials[w * BLOCKS_PER_CH + i];
#pragma unroll
    for (int m = 32; m; m >>= 1) sum += __shfl_xor(sum, m);
    if (lane == 0) {
        float mi = digammaf_dev((float)KNN) + digammaf_dev((float)HW)
                 - sum / (float)HW;
        out[w] = fmaxf(mi, 0.f);
    }
}

extern "C" void kernel_launch(void* const* d_in, const int* in_sizes, int n_in,
                              void* d_out, int out_size, void* d_ws, size_t ws_size,
                              hipStream_t stream) {
    const float* x = (const float*)d_in[0];
    const float* y = (const float*)d_in[1];
    float* out = (float*)d_out;
    float* ws  = (float*)d_ws;   // all read regions fully rewritten every call

    knnmi_bucketize<<<2 * NCH, 256, 0, stream>>>(x, y, ws);
    knnmi_rows<<<NBLOCKS, TPB, 0, stream>>>(ws);
    knnmi_final<<<1, NCH * 64, 0, stream>>>(ws, out);
}

// Round 13
// 31.007 us; speedup vs baseline: 2.3050x; 1.0591x over previous
//
#include <hip/hip_runtime.h>
#include <math.h>

#define HW 4096
#define NCH 4
#define TPB 256                               // 4 waves/block
#define ROWS_PER_BLOCK 16                     // contiguous rows, G=16
#define BLOCKS_PER_CH 256
#define NBLOCKS (NCH * BLOCKS_PER_CH)         // 1024
#define KNN 5
#define WINB 544                              // shared block window (ranks)

#define NBINS 512
#define BLO   (-6.0f)
#define BDELTA 0.0234375f      // 12/512, exact in fp32
#define BINV  (512.0f / 12.0f)
#define SLOP  1e-5f            // >> fp rounding of bin/edge math, << BDELTA
#define INFT  3.4e38f

// ws layout (float idx): bxx[4][4096]@0, bxy@16384, by@32768,
// prefX int@49152 (4*513), prefY after it, partials@57344 (1024 floats).
#define WS_BXY   16384
#define WS_BY    32768
#define WS_PREF  49152
#define WS_PART  57344

__device__ __forceinline__ int binOf(float v) {
    int b = (int)floorf((v - BLO) * BINV);
    return min(max(b, 0), NBINS - 1);
}

// digamma for positive integer args. Shift to >= 6 + asymptotic. ~1e-7.
__device__ __forceinline__ float digammaf_dev(float x) {
    float r = 0.f;
    while (x < 6.f) { r -= 1.f / x; x += 1.f; }
    float f = 1.f / x, f2 = f * f;
    return logf(x) - 0.5f * f
         - f2 * (1.f / 12.f - f2 * (1.f / 120.f - f2 * (1.f / 252.f))) + r;
}

// Insert d into ascending sorted 6-list (drop max): 6 independent med3.
__device__ __forceinline__ void insert6(float (&s)[6], float d) {
    float n0 = fminf(s[0], d);
    float n1 = __builtin_amdgcn_fmed3f(s[0], s[1], d);
    float n2 = __builtin_amdgcn_fmed3f(s[1], s[2], d);
    float n3 = __builtin_amdgcn_fmed3f(s[2], s[3], d);
    float n4 = __builtin_amdgcn_fmed3f(s[3], s[4], d);
    float n5 = __builtin_amdgcn_fmed3f(s[4], s[5], d);
    s[0] = n0; s[1] = n1; s[2] = n2; s[3] = n3; s[4] = n4; s[5] = n5;
}

// --------- Kernel 0: bucketize; 8 blocks = (channel x side) ----------------
__global__ __launch_bounds__(256) void knnmi_bucketize(const float* __restrict__ x,
                                                       const float* __restrict__ y,
                                                       float* __restrict__ ws) {
    __shared__ int h[NBINS];          // histogram, then running starts
    const int c    = blockIdx.x >> 1;
    const int side = blockIdx.x & 1;  // 0 = X pairs, 1 = Y values
    const int t    = threadIdx.x;
    const float* src  = (side == 0 ? x : y) + c * HW;
    const float* ysrc = y + c * HW;
    int* pref = (int*)ws + WS_PREF + (side ? NCH * (NBINS + 1) : 0) + c * (NBINS + 1);

    for (int i = t; i < NBINS; i += 256) h[i] = 0;
    __syncthreads();

    float vx[16], vy[16];
    int bn[16];
#pragma unroll
    for (int k = 0; k < 16; ++k) {            // one read pass, regs hold all
        int i = t + k * 256;
        float v = src[i];
        vx[k] = v;
        vy[k] = (side == 0) ? ysrc[i] : 0.f;
        bn[k] = binOf(v);
        atomicAdd(&h[bn[k]], 1);
    }
    __syncthreads();

    if (t < 64) {                             // single-wave scan, no barriers
        int sinc[8];
        {
            sinc[0] = h[t * 8 + 0];
#pragma unroll
            for (int j = 1; j < 8; ++j) sinc[j] = sinc[j - 1] + h[t * 8 + j];
        }
        int tot = sinc[7], inc = tot;
#pragma unroll
        for (int off = 1; off < 64; off <<= 1) {
            int u = __shfl_up(inc, off);
            if (t >= off) inc += u;
        }
        int ex = inc - tot;                   // exclusive prefix across lanes
#pragma unroll
        for (int j = 0; j < 8; ++j) {
            int st = ex + (j ? sinc[j - 1] : 0);
            h[t * 8 + j]    = st;
            pref[t * 8 + j] = st;
        }
        if (t == 63) pref[NBINS] = HW;
    }
    __syncthreads();

    if (side == 0) {
        float* bxx = ws + c * HW;
        float* bxy = ws + WS_BXY + c * HW;
#pragma unroll
        for (int k = 0; k < 16; ++k) {
            int pos = atomicAdd(&h[bn[k]], 1);
            bxx[pos] = vx[k];
            bxy[pos] = vy[k];
        }
    } else {
        float* by = ws + WS_BY + c * HW;
#pragma unroll
        for (int k = 0; k < 16; ++k) {
            int pos = atomicAdd(&h[bn[k]], 1);
            by[pos] = vx[k];
        }
    }
}

// --------- Kernel 1: contiguous rows, tiny LDS window, global counts -------
__global__ __launch_bounds__(TPB, 6) void knnmi_rows(float* __restrict__ ws) {
    __shared__ float2 swin[WINB];         // 4.25 KB: block's shared window
    __shared__ float red[ROWS_PER_BLOCK];

    const int c  = blockIdx.x >> 8;       // channel
    const int rb = blockIdx.x & 255;      // block within channel
    const int R0 = rb * ROWS_PER_BLOCK;   // first (contiguous) row
    const float* bxx = ws + c * HW;
    const float* bxy = ws + WS_BXY + c * HW;
    const float* by  = ws + WS_BY  + c * HW;
    const int* pfx = (const int*)ws + WS_PREF + c * (NBINS + 1);
    const int* pfy = (const int*)ws + WS_PREF + NCH * (NBINS + 1) + c * (NBINS + 1);

    // Shared window [LO, LO+WINB) covers every row's +-256 ranks.
    int LO = R0 - 256;
    LO = max(LO, 0); LO = min(LO, HW - WINB); LO &= ~3;   // float4-aligned
    const int HI = LO + WINB;

    if (threadIdx.x < WINB / 4) {         // stage 136 float4-pairs, 1 iter
        float4 xv = ((const float4*)(bxx + LO))[threadIdx.x];
        float4 yv = ((const float4*)(bxy + LO))[threadIdx.x];
        ((float4*)swin)[2 * threadIdx.x]     = make_float4(xv.x, yv.x, xv.y, yv.y);
        ((float4*)swin)[2 * threadIdx.x + 1] = make_float4(xv.z, yv.z, xv.w, yv.w);
    }
    __syncthreads();

    const int wv   = threadIdx.x >> 6;    // wave 0..3
    const int lane = threadIdx.x & 63;
    const int l    = lane & 15;           // lane within 16-lane group
    const int g    = lane >> 4;           // group (row) within wave
    const int q    = wv * 4 + g;          // 0..15
    const int p    = R0 + q;              // this group's row

    const float xi = swin[p - LO].x;
    const float yi = swin[p - LO].y;

    float s[6];
#pragma unroll
    for (int k = 0; k < 6; ++k) s[k] = INFT;

    // Scan the whole window: 17 iters x ds_read_b128 (all groups read the
    // same addresses -> broadcast, conflict-free). Includes self (d=0).
    const float4* f4 = (const float4*)swin;
#pragma unroll 4
    for (int it = 0; it < WINB / 32; ++it) {
        float4 pp = f4[it * 16 + l];
        insert6(s, fmaxf(fabsf(xi - pp.x), fabsf(yi - pp.y)));
        insert6(s, fmaxf(fabsf(xi - pp.z), fabsf(yi - pp.w)));
    }

    // Merge 16 per-lane sorted 6-lists (4 butterfly stages).
#pragma unroll
    for (int m = 1; m < 16; m <<= 1) {
        float o[6];
#pragma unroll
        for (int k = 0; k < 6; ++k) o[k] = __shfl_xor(s[k], m);
#pragma unroll
        for (int k = 0; k < 6; ++k) insert6(s, o[k]);
    }
    float eps = s[5];    // candidate (k+1)-th smallest (window-local)

    // Post-merge exactness check: any unscanned j has fl|xi-xj| >= edge
    // bound (bucket order => bin(x_j) bounded by the window-edge bins).
    float eL = INFT, eR = INFT;
    if (LO > 0) {
        int b = binOf(bxx[LO - 1]);
        eL = xi - (BLO + (float)(b + 1) * BDELTA + SLOP);
    }
    if (HI < HW) {
        int b = binOf(bxx[HI]);
        eR = (BLO + (float)b * BDELTA - SLOP) - xi;
    }
    const bool ok = (eps <= eL) && (eps <= eR);

    // Rare fallback: whole-wave exact brute scan of all 4096 (from L2).
    unsigned long long bad = __ballot((l == 0) && !ok);
    while (bad) {
        int bit = (int)__ffsll((unsigned long long)bad) - 1;
        bad &= bad - 1;
        const int tg = bit >> 4;                      // failed group in wave
        const int pt = R0 + wv * 4 + tg;
        const float xt = swin[pt - LO].x, yt = swin[pt - LO].y;
        float s3[6];
#pragma unroll
        for (int k = 0; k < 6; ++k) s3[k] = INFT;
        for (int it = 0; it < HW / 256; ++it) {       // 16 iters, G=64
            float4 xv = ((const float4*)bxx)[it * 64 + lane];
            float4 yv = ((const float4*)bxy)[it * 64 + lane];
            insert6(s3, fmaxf(fabsf(xt - xv.x), fabsf(yt - yv.x)));
            insert6(s3, fmaxf(fabsf(xt - xv.y), fabsf(yt - yv.y)));
            insert6(s3, fmaxf(fabsf(xt - xv.z), fabsf(yt - yv.z)));
            insert6(s3, fmaxf(fabsf(xt - xv.w), fabsf(yt - yv.w)));
        }
#pragma unroll
        for (int m = 1; m < 64; m <<= 1) {
            float o[6];
#pragma unroll
            for (int k = 0; k < 6; ++k) o[k] = __shfl_xor(s3[k], m);
#pragma unroll
            for (int k = 0; k < 6; ++k) insert6(s3, o[k]);
        }
        if (g == tg) eps = s3[5];                     // exact global 6th
    }

    // nx: interior bins by prefix-diff + exact scan of boundary bins (L2).
    int nx = 0;
    {
        int loB = binOf(xi - eps), hiB = binOf(xi + eps);
        int fLo = loB + 2, fHi = hiB - 2;
        if (fLo <= fHi) {
            if (l == 0) nx += pfx[fHi + 1] - pfx[fLo];
            int a0 = pfx[max(loB - 1, 0)], a1 = pfx[min(loB + 1, NBINS - 1) + 1];
            int b0 = pfx[max(hiB - 1, 0)], b1 = pfx[min(hiB + 1, NBINS - 1) + 1];
            for (int tt = a0 + l; tt < a1; tt += 16) nx += (fabsf(bxx[tt] - xi) < eps);
            for (int tt = b0 + l; tt < b1; tt += 16) nx += (fabsf(bxx[tt] - xi) < eps);
        } else {
            int a0 = pfx[max(loB - 1, 0)], a1 = pfx[min(hiB + 1, NBINS - 1) + 1];
            for (int tt = a0 + l; tt < a1; tt += 16) nx += (fabsf(bxx[tt] - xi) < eps);
        }
    }
    // ny: same scheme on the y-bucketed array (L2).
    int ny = 0;
    {
        int loB = binOf(yi - eps), hiB = binOf(yi + eps);
        int fLo = loB + 2, fHi = hiB - 2;
        if (fLo <= fHi) {
            if (l == 0) ny += pfy[fHi + 1] - pfy[fLo];
            int a0 = pfy[max(loB - 1, 0)], a1 = pfy[min(loB + 1, NBINS - 1) + 1];
            int b0 = pfy[max(hiB - 1, 0)], b1 = pfy[min(hiB + 1, NBINS - 1) + 1];
            for (int tt = a0 + l; tt < a1; tt += 16) ny += (fabsf(by[tt] - yi) < eps);
            for (int tt = b0 + l; tt < b1; tt += 16) ny += (fabsf(by[tt] - yi) < eps);
        } else {
            int a0 = pfy[max(loB - 1, 0)], a1 = pfy[min(hiB + 1, NBINS - 1) + 1];
            for (int tt = a0 + l; tt < a1; tt += 16) ny += (fabsf(by[tt] - yi) < eps);
        }
    }

    int pk = (nx << 16) | ny;                 // totals <= 4096, no carry
#pragma unroll
    for (int m = 1; m < 16; m <<= 1) pk += __shfl_xor(pk, m);

    if (l == 0)
        red[q] = digammaf_dev((float)(pk >> 16)) + digammaf_dev((float)(pk & 0xffff));
    __syncthreads();

    if (threadIdx.x == 0) {
        float v = 0.f;
#pragma unroll
        for (int k = 0; k < ROWS_PER_BLOCK; ++k) v += red[k];
        (ws + WS_PART)[blockIdx.x] = v;
    }
}

// --------- Kernel 2: finalize ---------------------------------------------
__global__ void knnmi_final(const float* __restrict__ ws, float* __restrict__ out) {
    const float* partials = ws + WS_PART;
    const int w    = threadIdx.x >> 6;    // wave = channel
    const int lane = threadIdx.x & 63;
    float sum = 0.f;
#pragma unroll
    for (int i = lane; i < BLOCKS_PER_CH; i += 64)
        sum += partials[w * BLOCKS_PER_CH + i];
#pragma unroll
    for (int m = 32; m; m >>= 1) sum += __shfl_xor(sum, m);
    if (lane == 0) {
        float mi = digammaf_dev((float)KNN) + digammaf_dev((float)HW)
                 - sum / (float)HW;
        out[w] = fmaxf(mi, 0.f);
    }
}

extern "C" void kernel_launch(void* const* d_in, const int* in_sizes, int n_in,
                              void* d_out, int out_size, void* d_ws, size_t ws_size,
                              hipStream_t stream) {
    const float* x = (const float*)d_in[0];
    const float* y = (const float*)d_in[1];
    float* out = (float*)d_out;
    float* ws  = (float*)d_ws;   // all read regions fully rewritten every call

    knnmi_bucketize<<<2 * NCH, 256, 0, stream>>>(x, y, ws);
    knnmi_rows<<<NBLOCKS, TPB, 0, stream>>>(ws);
    knnmi_final<<<1, NCH * 64, 0, stream>>>(ws, out);
}